// Round 1
// baseline (15075.046 us; speedup 1.0000x reference)
//
#include <hip/hip_runtime.h>

#define TS 512
#define NB 64
#define FIN 512
#define HD 512

// 4 islands (16 batches each), one per XCD 0..3 (round-robin wg&7 -> XCD, m09).
// Island = 32 WGs on one XCD; each WG owns 16 hidden dims (64 gate rows).
#define NISL 4
#define MB 16                       // batches per island
#define HW 16                       // hidden dims per WG
#define ISL_U64 (MB * HD / 2)       // 4096 u64 per island per rotation buffer
#define BUF_U64 (NISL * ISL_U64)    // 16384 u64 per rotation buffer
#define SLOW_OFF (4 * BUF_U64)      // fast [4][NISL][ISL_U64] then slow mirror
#define R_FAST 24                   // local-L2 poll rounds before IF fallback

typedef short bf16x8 __attribute__((ext_vector_type(8)));
typedef float f32x4 __attribute__((ext_vector_type(4)));

__device__ __forceinline__ unsigned short f2bf(float f) {
  union { float f; unsigned int i; } v; v.f = f;
  unsigned int r = v.i + 0x7fffu + ((v.i >> 16) & 1u);  // RNE
  return (unsigned short)(r >> 16);
}
__device__ __forceinline__ bf16x8 packv(f32x4 a, f32x4 b) {
  bf16x8 r;
#pragma unroll
  for (int i = 0; i < 4; ++i) r[i] = (short)f2bf(a[i]);
#pragma unroll
  for (int i = 0; i < 4; ++i) r[4 + i] = (short)f2bf(b[i]);
  return r;
}
__device__ __forceinline__ float sigm(float x) { return 1.0f / (1.0f + __expf(-x)); }
__device__ __forceinline__ float tanh_(float x) { return 1.0f - 2.0f / (__expf(2.0f * x) + 1.0f); }

// XCD-local poll load: sc0 bypasses this CU's (possibly stale) L1 but hits the
// XCD-shared L2, where same-XCD producers' plain stores land (vector L1 is
// write-through). Result invalid until caller's s_waitcnt vmcnt(0).
template <int OFF>
__device__ __forceinline__ unsigned long long ld_l2(const unsigned long long* p) {
  unsigned long long v;
  asm volatile("global_load_dwordx2 %0, %1, off offset:%2 sc0"
               : "=v"(v) : "v"(p), "i"(OFF));
  return v;
}

// Persistent fused LSTM. fp32 in/out, bf16 MFMA internal.
// Grid: 256 WGs; WGs with (wg&7)>=4 exit (XCDs 4..7 idle). Active WG(bg,hg):
// bg = wg&7 (island / 16 batches), hg = wg>>3 (16 hidden dims).
// Waves 0,1: x @ W_ih^T (K halves). Waves 2,3: h @ W_hh^T (K halves).
// Weights (2 x 64 rows x 512) live in bf16 register fragments for all 512 steps.
// h exchange: tagged u64 {tag=t+1 | 2xbf16}, 4 rotating buffers, published to
//   (a) FAST buffer via plain (workgroup-scope) store -> stays in this XCD's L2,
//       polled by island peers with sc0 loads (intra-XCD L2 round trip), and
//   (b) SLOW mirror via RELAXED agent atomics (IF point-coherent) -- correctness
//       fallback if WG->XCD placement or sc0 semantics differ. Tags make any
//       mix of stale/fresh reads safe; placement is a perf hint only (G16).
__global__ void __launch_bounds__(256, 1) lstm_persist(
    const float* __restrict__ seq,
    const float* __restrict__ w_ih,
    const float* __restrict__ w_hh,
    const float* __restrict__ b_ih,
    const float* __restrict__ b_hh,
    float* __restrict__ out,
    unsigned long long* __restrict__ hbuf)  // [2][4][NISL][ISL_U64] = 1 MiB d_ws
{
  const int wg = blockIdx.x;
  const int isl = wg & 7;
  if (isl >= NISL) return;          // idle half: XCDs 4..7
  const int bg   = isl;
  const int hg   = wg >> 3;         // 0..31
  const int tid  = threadIdx.x;
  const int wave = tid >> 6;
  const int lane = tid & 63;
  const int mb0  = bg * MB;
  const int hid0 = hg * HW;
  const int nloc = lane & 15;       // A: m (batch). B: n (gate col). D: col = n.
  const int quad = lane >> 4;       // A/B: k-chunk. D: row block (m).

  __shared__ __align__(16) float gred[2][4][64][20];  // [t&1][wave][n][m+pad] 40KiB

  const float* W = (wave < 2) ? w_ih : w_hh;
  const int k0 = (wave & 1) * 256;  // this wave's K half

  // ---- step-invariant weight fragments -> bf16 registers (tile nt == gate) ----
  bf16x8 bfrag[4][8];  // [ntile=gate][kiter] = 128 VGPRs
#pragma unroll
  for (int nt = 0; nt < 4; ++nt) {
    const float* src = W + (size_t)(nt * HD + hid0 + nloc) * FIN + k0 + quad * 8;
#pragma unroll
    for (int kk = 0; kk < 8; ++kk)
      bfrag[nt][kk] = packv(*(const f32x4*)(src + kk * 32),
                            *(const f32x4*)(src + kk * 32 + 4));
  }

  // ---- cell state: ALL 256 threads own one (batch,hid) cell ----
  const int cb = tid >> 4;   // local batch 0..15
  const int cj = tid & 15;   // local hid 0..15
  float bias_[4];
#pragma unroll
  for (int g = 0; g < 4; ++g) {
    int r = g * HD + hid0 + cj;
    bias_[g] = b_ih[r] + b_hh[r];
  }
  float cprev = 0.0f;

  const size_t ax_base  = (size_t)(mb0 + nloc) * FIN + k0 + quad * 8;
  const int    row_half = nloc * (HD / 2) + (k0 >> 1);  // island-local u64 row base

  // ---- software-prefetch x(0) into registers (waves 0,1) ----
  f32x4 xpf[16];
  if (wave < 2) {
    const float* ap = seq + ax_base;
#pragma unroll
    for (int kk = 0; kk < 8; ++kk) {
      xpf[2 * kk]     = *(const f32x4*)(ap + kk * 32);
      xpf[2 * kk + 1] = *(const f32x4*)(ap + kk * 32 + 4);
    }
  }

  for (int t = 0; t < TS; ++t) {
    f32x4 acc[4];
#pragma unroll
    for (int nt = 0; nt < 4; ++nt) acc[nt] = (f32x4){0.f, 0.f, 0.f, 0.f};

    if (wave < 2) {
      // x-projection from prefetched regs; no cross-WG dependency
      bf16x8 afr[8];
#pragma unroll
      for (int kk = 0; kk < 8; ++kk) afr[kk] = packv(xpf[2 * kk], xpf[2 * kk + 1]);
#pragma unroll
      for (int kk = 0; kk < 8; ++kk)
#pragma unroll
        for (int nt = 0; nt < 4; ++nt)
          acc[nt] = __builtin_amdgcn_mfma_f32_16x16x32_bf16(afr[kk], bfrag[nt][kk],
                                                            acc[nt], 0, 0, 0);
      int tn = (t + 1 < TS) ? t + 1 : TS - 1;
      const float* ap = seq + (size_t)tn * (NB * FIN) + ax_base;
#pragma unroll
      for (int kk = 0; kk < 8; ++kk) {
        xpf[2 * kk]     = *(const f32x4*)(ap + kk * 32);
        xpf[2 * kk + 1] = *(const f32x4*)(ap + kk * 32 + 4);
      }
    } else if (t > 0) {
      // gather tagged h(t-1): 32 u64 per lane, fast (XCD L2) then slow (IF)
      const size_t boff = (size_t)((t - 1) & 3) * BUF_U64 + bg * ISL_U64 + row_half;
      const unsigned long long* hfq = hbuf + boff + quad * 4;        // fast base
      const unsigned long long* hs  = hbuf + SLOW_OFF + boff;        // slow base
      unsigned long long hv[32];
      unsigned int done = 0;

      for (int r = 0; r < R_FAST && done != 0xffffffffu; ++r) {
#define FPOLL(i) if (!((done >> (i)) & 1u)) \
          hv[(i)] = ld_l2<(((i) >> 2) * 128 + ((i) & 3) * 8)>(hfq);
        FPOLL(0)  FPOLL(1)  FPOLL(2)  FPOLL(3)  FPOLL(4)  FPOLL(5)  FPOLL(6)  FPOLL(7)
        FPOLL(8)  FPOLL(9)  FPOLL(10) FPOLL(11) FPOLL(12) FPOLL(13) FPOLL(14) FPOLL(15)
        FPOLL(16) FPOLL(17) FPOLL(18) FPOLL(19) FPOLL(20) FPOLL(21) FPOLL(22) FPOLL(23)
        FPOLL(24) FPOLL(25) FPOLL(26) FPOLL(27) FPOLL(28) FPOLL(29) FPOLL(30) FPOLL(31)
#undef FPOLL
        asm volatile("s_waitcnt vmcnt(0)" ::: "memory");
        __builtin_amdgcn_sched_barrier(0);  // rule 18: no VALU hoisted above wait
        unsigned int nd = done;
#pragma unroll
        for (int i = 0; i < 32; ++i)
          if (!((nd >> i) & 1u) && (int)(unsigned int)(hv[i] >> 32) >= t)
            nd |= 1u << i;
        done = nd;
      }
      // IF fallback: correct for ANY WG->XCD placement (baseline-proven path)
      for (int r = 0; r < (1 << 20) && done != 0xffffffffu; ++r) {
#pragma unroll
        for (int i = 0; i < 32; ++i)
          if (!((done >> i) & 1u))
            hv[i] = __hip_atomic_load(hs + ((i >> 2) * 16 + quad * 4 + (i & 3)),
                                      __ATOMIC_RELAXED, __HIP_MEMORY_SCOPE_AGENT);
        unsigned int nd = done;
#pragma unroll
        for (int i = 0; i < 32; ++i)
          if (!((nd >> i) & 1u) && (int)(unsigned int)(hv[i] >> 32) >= t)
            nd |= 1u << i;
        done = nd;
        if (done != 0xffffffffu) __builtin_amdgcn_s_sleep(1);
      }

      bf16x8 afr[8];
#pragma unroll
      for (int kk = 0; kk < 8; ++kk) {
        union { unsigned int d[4]; bf16x8 v; } u;
#pragma unroll
        for (int j = 0; j < 4; ++j) u.d[j] = (unsigned int)hv[kk * 4 + j];
        afr[kk] = u.v;
      }
#pragma unroll
      for (int kk = 0; kk < 8; ++kk)
#pragma unroll
        for (int nt = 0; nt < 4; ++nt)
          acc[nt] = __builtin_amdgcn_mfma_f32_16x16x32_bf16(afr[kk], bfrag[nt][kk],
                                                            acc[nt], 0, 0, 0);
    }
    // D layout: col = lane&15 (= n), row m = quad*4 + reg
#pragma unroll
    for (int nt = 0; nt < 4; ++nt)
      *(f32x4*)&gred[t & 1][wave][nt * 16 + nloc][quad * 4] = acc[nt];
    __syncthreads();  // the only barrier per step (gred is double-buffered)

    // ---- cell update: all 256 threads ----
    float gs[4];
#pragma unroll
    for (int g = 0; g < 4; ++g) {
      int n = g * 16 + cj;
      gs[g] = bias_[g] + gred[t & 1][0][n][cb] + gred[t & 1][1][n][cb] +
              gred[t & 1][2][n][cb] + gred[t & 1][3][n][cb];
    }
    float ig = sigm(gs[0]);
    float fg = sigm(gs[1]);
    float gg = tanh_(gs[2]);
    float og = sigm(gs[3]);
    float c  = fg * cprev + ig * gg;
    cprev = c;
    float h  = og * tanh_(c);

    // publish FIRST (consumers wait on it), out[] stores after
    unsigned int hu = (unsigned int)f2bf(h);
    unsigned int ho = __shfl_down(hu, 1);
    if ((tid & 1) == 0) {  // cj even: pack (cj, cj+1)
      unsigned long long tv =
          ((unsigned long long)(unsigned int)(t + 1) << 32) |
          (unsigned long long)(hu | (ho << 16));
      size_t slot = (size_t)(t & 3) * BUF_U64 + bg * ISL_U64 +
                    (size_t)((cb * HD + hid0 + cj) >> 1);
      // fast: plain store -> write-through L1 into this XCD's shared L2
      __hip_atomic_store(hbuf + slot, tv, __ATOMIC_RELAXED,
                         __HIP_MEMORY_SCOPE_WORKGROUP);
      // slow mirror: IF point-coherent, placement-independent correctness
      __hip_atomic_store(hbuf + SLOW_OFF + slot, tv, __ATOMIC_RELAXED,
                         __HIP_MEMORY_SCOPE_AGENT);
    }
    size_t o = (size_t)t * (NB * HD) + (size_t)(mb0 + cb) * HD + hid0 + cj;
    out[o] = h;
    out[(size_t)TS * NB * HD + o] = c;
    // no second barrier: next step's gred writes hit buffer (t+1)&1
  }
}

extern "C" void kernel_launch(void* const* d_in, const int* in_sizes, int n_in,
                              void* d_out, int out_size, void* d_ws, size_t ws_size,
                              hipStream_t stream) {
  const float* seq = (const float*)d_in[0];
  const float* wih = (const float*)d_in[1];
  const float* whh = (const float*)d_in[2];
  const float* bih = (const float*)d_in[3];
  const float* bhh = (const float*)d_in[4];
  float* out = (float*)d_out;
  unsigned long long* hbuf = (unsigned long long*)d_ws;  // 2*4*16384*8 = 1 MiB
  hipLaunchKernelGGL(lstm_persist, dim3(256), dim3(256), 0, stream,
                     seq, wih, whh, bih, bhh, out, hbuf);
}

// Round 2
// 4711.795 us; speedup vs baseline: 3.1994x; 3.1994x over previous
//
#include <hip/hip_runtime.h>

#define TS 512
#define NB 64
#define FIN 512
#define HD 512
#define HBUF_U64 (NB * HD / 2)   // 16384 u64 per buffer; 4 buffers = 512 KiB
#define FLAG_OFF (4 * HBUF_U64)  // u32 flags[256] after the 4 rotating buffers

typedef short bf16x8 __attribute__((ext_vector_type(8)));
typedef float f32x4 __attribute__((ext_vector_type(4)));

__device__ __forceinline__ unsigned short f2bf(float f) {
  union { float f; unsigned int i; } v; v.f = f;
  unsigned int r = v.i + 0x7fffu + ((v.i >> 16) & 1u);  // RNE
  return (unsigned short)(r >> 16);
}
__device__ __forceinline__ bf16x8 packv(f32x4 a, f32x4 b) {
  bf16x8 r;
#pragma unroll
  for (int i = 0; i < 4; ++i) r[i] = (short)f2bf(a[i]);
#pragma unroll
  for (int i = 0; i < 4; ++i) r[4 + i] = (short)f2bf(b[i]);
  return r;
}
__device__ __forceinline__ float sigm(float x) { return 1.0f / (1.0f + __expf(-x)); }
__device__ __forceinline__ float tanh_(float x) { return 1.0f - 2.0f / (__expf(2.0f * x) + 1.0f); }

// Persistent fused LSTM. fp32 in, fp32 out, bf16 MFMA internal.
// Grid: 256 WGs = 4 batch groups (bg) x 64 hidden groups (hg).
// WG(bg,hg): batches [bg*16,+16), hidden [hg*8,+8) -> 32 gate rows.
// Waves 0,1: x @ W_ih^T (K halves). Waves 2,3: h @ W_hh^T (K halves).
// Weights as bf16 fragments in registers for all 512 steps.
// h exchange: tagged u64 {tag=t+1 | 2xbf16} via RELAXED agent atomics (IF
// point-coherent). 4 rotating buffers make overwrite provably safe.
// NEW vs 3950us baseline: per-producer monotonic u32 flag. Consumers do ONE
// optimistic tagged-data round; if incomplete, spin on a 1-load/lane flag poll
// (64 flags = one coalesced wave load) instead of re-issuing 32 u64 loads per
// round, then one final tagged round. Tags still gate correctness -- the flag
// is a traffic hint only (32x less IF poll traffic -> publish stores uncontended).
__global__ void __launch_bounds__(256, 1) lstm_persist(
    const float* __restrict__ seq,
    const float* __restrict__ w_ih,
    const float* __restrict__ w_hh,
    const float* __restrict__ b_ih,
    const float* __restrict__ b_hh,
    float* __restrict__ out,
    unsigned long long* __restrict__ hbuf)  // d_ws: 512 KiB data + 1 KiB flags
{
  const int wg   = blockIdx.x;
  const int hg   = wg & 63;
  const int bg   = wg >> 6;
  const int tid  = threadIdx.x;
  const int wave = tid >> 6;
  const int lane = tid & 63;
  const int mb0  = bg * 16;
  const int hid0 = hg * 8;
  const int nloc = lane & 15;   // A: m (batch). B: n (gate col). C/D: col = n.
  const int quad = lane >> 4;   // A/B: k-chunk. C/D: row block (m).

  __shared__ __align__(16) float gred[2][4][32][20];  // [t&1][wave][n][m +pad]

  const float* W = (wave < 2) ? w_ih : w_hh;
  const int k0 = (wave & 1) * 256;  // this wave's K half

  // ---- step-invariant weight fragments -> bf16 registers ----
  bf16x8 bfrag[2][8];  // [ntile][kiter]
#pragma unroll
  for (int nt = 0; nt < 2; ++nt) {
    int n = nt * 16 + nloc;
    int grow = (n >> 3) * HD + hid0 + (n & 7);  // gate row: gtype*512 + hid0 + j
    const float* src = W + (size_t)grow * FIN + k0 + quad * 8;
#pragma unroll
    for (int kk = 0; kk < 8; ++kk)
      bfrag[nt][kk] = packv(*(const f32x4*)(src + kk * 32),
                            *(const f32x4*)(src + kk * 32 + 4));
  }

  // ---- cell-thread state (threads 0..127: one (batch,hid) each) ----
  float bias_[4] = {0.f, 0.f, 0.f, 0.f};
  float cprev = 0.0f;
  int cb = 0, cj = 0;
  if (tid < 128) {
    cb = tid >> 3;   // local batch 0..15
    cj = tid & 7;    // local hid 0..7
#pragma unroll
    for (int g = 0; g < 4; ++g) {
      int r = g * HD + hid0 + cj;
      bias_[g] = b_ih[r] + b_hh[r];
    }
  }

  const size_t ax_base = (size_t)(mb0 + nloc) * FIN + k0 + quad * 8;
  const int hrow_u64 = ((mb0 + nloc) * HD + k0) >> 1;  // reader base in u64 units

  // ---- software-prefetch x(0) into registers (waves 0,1) ----
  f32x4 xpf[16];
  if (wave < 2) {
    const float* ap = seq + ax_base;
#pragma unroll
    for (int kk = 0; kk < 8; ++kk) {
      xpf[2 * kk]     = *(const f32x4*)(ap + kk * 32);
      xpf[2 * kk + 1] = *(const f32x4*)(ap + kk * 32 + 4);
    }
  }

  for (int t = 0; t < TS; ++t) {
    f32x4 acc0 = {0.f, 0.f, 0.f, 0.f};
    f32x4 acc1 = {0.f, 0.f, 0.f, 0.f};

    if (wave < 2) {
      // x-projection from prefetched regs; no cross-WG dependency
      bf16x8 afr[8];
#pragma unroll
      for (int kk = 0; kk < 8; ++kk) afr[kk] = packv(xpf[2 * kk], xpf[2 * kk + 1]);
#pragma unroll
      for (int kk = 0; kk < 8; ++kk) {
        acc0 = __builtin_amdgcn_mfma_f32_16x16x32_bf16(afr[kk], bfrag[0][kk], acc0, 0, 0, 0);
        acc1 = __builtin_amdgcn_mfma_f32_16x16x32_bf16(afr[kk], bfrag[1][kk], acc1, 0, 0, 0);
      }
      // prefetch x(t+1) (lands during the rest of this step)
      int tn = (t + 1 < TS) ? t + 1 : TS - 1;
      const float* ap = seq + (size_t)tn * (NB * FIN) + ax_base;
#pragma unroll
      for (int kk = 0; kk < 8; ++kk) {
        xpf[2 * kk]     = *(const f32x4*)(ap + kk * 32);
        xpf[2 * kk + 1] = *(const f32x4*)(ap + kk * 32 + 4);
      }
    } else if (t > 0) {
      const unsigned long long* hb =
          hbuf + (size_t)((t - 1) & 3) * HBUF_U64 + hrow_u64;
      const unsigned int* fl =
          (const unsigned int*)(hbuf + FLAG_OFF) + bg * 64;
      unsigned long long hv[32];
      unsigned int done = 0;

      // round 0: optimistic tagged-data read (catches already-published case)
#pragma unroll
      for (int i = 0; i < 32; ++i)
        hv[i] = __hip_atomic_load(hb + ((i >> 2) * 16 + quad * 4 + (i & 3)),
                                  __ATOMIC_RELAXED, __HIP_MEMORY_SCOPE_AGENT);
#pragma unroll
      for (int i = 0; i < 32; ++i)
        if ((int)(unsigned int)(hv[i] >> 32) >= t) done |= 1u << i;

      if (done != 0xffffffffu) {
        // cheap flag-hint poll: ONE dword per lane per round (vs 32 u64).
        // lane l watches producer WG (bg, hg=l); flag >= t means h(t-1) sent.
        for (int r = 0; r < 65536; ++r) {
          unsigned int f = __hip_atomic_load(fl + lane, __ATOMIC_RELAXED,
                                             __HIP_MEMORY_SCOPE_AGENT);
          if (__all((int)f >= t)) break;
        }
        // tagged-data rounds (usually exactly 1 now); tags gate correctness
        for (int r = 0; r < 8192 && done != 0xffffffffu; ++r) {
#pragma unroll
          for (int i = 0; i < 32; ++i)
            if (!((done >> i) & 1u))
              hv[i] = __hip_atomic_load(hb + ((i >> 2) * 16 + quad * 4 + (i & 3)),
                                        __ATOMIC_RELAXED, __HIP_MEMORY_SCOPE_AGENT);
          unsigned int nd = done;
#pragma unroll
          for (int i = 0; i < 32; ++i)
            if (!((nd >> i) & 1u) && (int)(unsigned int)(hv[i] >> 32) >= t)
              nd |= 1u << i;
          done = nd;
          if (done != 0xffffffffu) __builtin_amdgcn_s_sleep(1);
        }
      }

      bf16x8 afr[8];
#pragma unroll
      for (int kk = 0; kk < 8; ++kk) {
        union { unsigned int d[4]; bf16x8 v; } u;
#pragma unroll
        for (int j = 0; j < 4; ++j) u.d[j] = (unsigned int)hv[kk * 4 + j];
        afr[kk] = u.v;
      }
#pragma unroll
      for (int kk = 0; kk < 8; ++kk) {
        acc0 = __builtin_amdgcn_mfma_f32_16x16x32_bf16(afr[kk], bfrag[0][kk], acc0, 0, 0, 0);
        acc1 = __builtin_amdgcn_mfma_f32_16x16x32_bf16(afr[kk], bfrag[1][kk], acc1, 0, 0, 0);
      }
    }
    // C/D layout: col = lane&15 (= n), row m = quad*4 + reg
    *(f32x4*)&gred[t & 1][wave][nloc][quad * 4]      = acc0;
    *(f32x4*)&gred[t & 1][wave][16 + nloc][quad * 4] = acc1;
    __syncthreads();  // the only barrier per step (gred is double-buffered)

    if (tid < 128) {
      float gs[4];
#pragma unroll
      for (int g = 0; g < 4; ++g) {
        int n = g * 8 + cj;
        gs[g] = bias_[g] + gred[t & 1][0][n][cb] + gred[t & 1][1][n][cb] +
                gred[t & 1][2][n][cb] + gred[t & 1][3][n][cb];
      }
      float ig = sigm(gs[0]);
      float fg = sigm(gs[1]);
      float gg = tanh_(gs[2]);
      float og = sigm(gs[3]);
      float c  = fg * cprev + ig * gg;
      cprev = c;
      float h  = og * tanh_(c);
      size_t o = (size_t)t * (NB * HD) + (size_t)(mb0 + cb) * HD + hid0 + cj;
      // publish tagged h pair FIRST: even thread packs (cj, cj+1)
      unsigned int hu = (unsigned int)f2bf(h);
      unsigned int ho = __shfl_down(hu, 1);
      if ((tid & 1) == 0) {
        unsigned long long tv =
            ((unsigned long long)(unsigned int)(t + 1) << 32) |
            (unsigned long long)(hu | (ho << 16));
        int eidx = (mb0 + cb) * HD + hid0 + cj;  // cj even
        __hip_atomic_store(hbuf + (size_t)(t & 3) * HBUF_U64 + (eidx >> 1), tv,
                           __ATOMIC_RELAXED, __HIP_MEMORY_SCOPE_AGENT);
      }
      // flag hint (monotonic, relaxed; tags still gate correctness)
      if (tid == 0)
        __hip_atomic_store((unsigned int*)(hbuf + FLAG_OFF) + wg,
                           (unsigned int)(t + 1), __ATOMIC_RELAXED,
                           __HIP_MEMORY_SCOPE_AGENT);
      out[o] = h;
      out[(size_t)TS * NB * HD + o] = c;
    }
    // no second barrier: next step's gred writes hit buffer (t+1)&1
  }
}

extern "C" void kernel_launch(void* const* d_in, const int* in_sizes, int n_in,
                              void* d_out, int out_size, void* d_ws, size_t ws_size,
                              hipStream_t stream) {
  const float* seq = (const float*)d_in[0];
  const float* wih = (const float*)d_in[1];
  const float* whh = (const float*)d_in[2];
  const float* bih = (const float*)d_in[3];
  const float* bhh = (const float*)d_in[4];
  float* out = (float*)d_out;
  unsigned long long* hbuf = (unsigned long long*)d_ws;  // 512 KiB + 1 KiB flags
  hipLaunchKernelGGL(lstm_persist, dim3(256), dim3(256), 0, stream,
                     seq, wih, whh, bih, bhh, out, hbuf);
}

// Round 3
// 3397.138 us; speedup vs baseline: 4.4376x; 1.3870x over previous
//
#include <hip/hip_runtime.h>

#define TS 512
#define NB 64
#define FIN 512
#define HD 512
#define HBUF_U64 (NB * HD / 2)   // 16384 u64 per buffer; 4 buffers = 512 KiB in d_ws
#define R_FAST 16                // dwordx4 fast poll rounds before proven fallback

typedef short bf16x8 __attribute__((ext_vector_type(8)));
typedef float f32x4 __attribute__((ext_vector_type(4)));
typedef unsigned int u32x4 __attribute__((ext_vector_type(4)));

__device__ __forceinline__ unsigned short f2bf(float f) {
  union { float f; unsigned int i; } v; v.f = f;
  unsigned int r = v.i + 0x7fffu + ((v.i >> 16) & 1u);  // RNE
  return (unsigned short)(r >> 16);
}
__device__ __forceinline__ bf16x8 packv(f32x4 a, f32x4 b) {
  bf16x8 r;
#pragma unroll
  for (int i = 0; i < 4; ++i) r[i] = (short)f2bf(a[i]);
#pragma unroll
  for (int i = 0; i < 4; ++i) r[4 + i] = (short)f2bf(b[i]);
  return r;
}
__device__ __forceinline__ float sigm(float x) { return 1.0f / (1.0f + __expf(-x)); }
__device__ __forceinline__ float tanh_(float x) { return 1.0f - 2.0f / (__expf(2.0f * x) + 1.0f); }

// 16B device-coherent load: sc0 sc1 bypasses L1 AND the (per-XCD, non-coherent)
// L2 -- the same freshness path agent-scope atomic loads use (round-1 pinned:
// sc0 alone is served stale from local L2). Returns TWO tagged u64 per request:
// half the IF coherence-point request pressure of the per-u64 atomic poll.
// Result registers invalid until caller's s_waitcnt vmcnt(0).
template <int OFF>
__device__ __forceinline__ u32x4 ldx4_dev(const unsigned long long* p) {
  u32x4 v;
  asm volatile("global_load_dwordx4 %0, %1, off offset:%2 sc0 sc1"
               : "=v"(v) : "v"(p), "i"(OFF));
  return v;
}

// Persistent fused LSTM. fp32 in, fp32 out, bf16 MFMA internal.
// Grid: 256 WGs = 4 batch groups (bg) x 64 hidden groups (hg).
// WG(bg,hg): batches [bg*16,+16), hidden [hg*8,+8) -> 32 gate rows.
// Waves 0,1: x @ W_ih^T (K halves). Waves 2,3: h @ W_hh^T (K halves).
// Weights as bf16 fragments in registers for all 512 steps.
// h exchange: tagged u64 {tag=t+1 | 2xbf16} via RELAXED agent atomics (IF
// point-coherent), 4 rotating buffers. Consumers poll with MERGED
// detect+fetch rounds (the round-2 lesson: separating them serializes):
// fast rounds use 16B dwordx4 coherent loads (2 tagged u64 each, 2x fewer
// coherence-point requests), with per-u64 tags gating correctness; after
// R_FAST rounds fall back to the byte-identical proven atomic-u64 loop.
__global__ void __launch_bounds__(256, 1) lstm_persist(
    const float* __restrict__ seq,
    const float* __restrict__ w_ih,
    const float* __restrict__ w_hh,
    const float* __restrict__ b_ih,
    const float* __restrict__ b_hh,
    float* __restrict__ out,
    unsigned long long* __restrict__ hbuf)  // [4][NB*HD/2] tagged u64 in d_ws
{
  const int wg   = blockIdx.x;
  const int hg   = wg & 63;
  const int bg   = wg >> 6;
  const int tid  = threadIdx.x;
  const int wave = tid >> 6;
  const int lane = tid & 63;
  const int mb0  = bg * 16;
  const int hid0 = hg * 8;
  const int nloc = lane & 15;   // A: m (batch). B: n (gate col). C/D: col = n.
  const int quad = lane >> 4;   // A/B: k-chunk. C/D: row block (m).

  __shared__ __align__(16) float gred[2][4][32][20];  // [t&1][wave][n][m +pad]

  const float* W = (wave < 2) ? w_ih : w_hh;
  const int k0 = (wave & 1) * 256;  // this wave's K half

  // ---- step-invariant weight fragments -> bf16 registers ----
  bf16x8 bfrag[2][8];  // [ntile][kiter]
#pragma unroll
  for (int nt = 0; nt < 2; ++nt) {
    int n = nt * 16 + nloc;
    int grow = (n >> 3) * HD + hid0 + (n & 7);  // gate row: gtype*512 + hid0 + j
    const float* src = W + (size_t)grow * FIN + k0 + quad * 8;
#pragma unroll
    for (int kk = 0; kk < 8; ++kk)
      bfrag[nt][kk] = packv(*(const f32x4*)(src + kk * 32),
                            *(const f32x4*)(src + kk * 32 + 4));
  }

  // ---- cell-thread state (threads 0..127: one (batch,hid) each) ----
  float bias_[4] = {0.f, 0.f, 0.f, 0.f};
  float cprev = 0.0f;
  int cb = 0, cj = 0;
  if (tid < 128) {
    cb = tid >> 3;   // local batch 0..15
    cj = tid & 7;    // local hid 0..7
#pragma unroll
    for (int g = 0; g < 4; ++g) {
      int r = g * HD + hid0 + cj;
      bias_[g] = b_ih[r] + b_hh[r];
    }
  }

  const size_t ax_base = (size_t)(mb0 + nloc) * FIN + k0 + quad * 8;
  const int hrow_u64 = ((mb0 + nloc) * HD + k0) >> 1;  // reader base in u64 units

  // ---- software-prefetch x(0) into registers (waves 0,1) ----
  f32x4 xpf[16];
  if (wave < 2) {
    const float* ap = seq + ax_base;
#pragma unroll
    for (int kk = 0; kk < 8; ++kk) {
      xpf[2 * kk]     = *(const f32x4*)(ap + kk * 32);
      xpf[2 * kk + 1] = *(const f32x4*)(ap + kk * 32 + 4);
    }
  }

  for (int t = 0; t < TS; ++t) {
    f32x4 acc0 = {0.f, 0.f, 0.f, 0.f};
    f32x4 acc1 = {0.f, 0.f, 0.f, 0.f};

    if (wave < 2) {
      // x-projection from prefetched regs; no cross-WG dependency
      bf16x8 afr[8];
#pragma unroll
      for (int kk = 0; kk < 8; ++kk) afr[kk] = packv(xpf[2 * kk], xpf[2 * kk + 1]);
#pragma unroll
      for (int kk = 0; kk < 8; ++kk) {
        acc0 = __builtin_amdgcn_mfma_f32_16x16x32_bf16(afr[kk], bfrag[0][kk], acc0, 0, 0, 0);
        acc1 = __builtin_amdgcn_mfma_f32_16x16x32_bf16(afr[kk], bfrag[1][kk], acc1, 0, 0, 0);
      }
      // prefetch x(t+1) (lands during the rest of this step)
      int tn = (t + 1 < TS) ? t + 1 : TS - 1;
      const float* ap = seq + (size_t)tn * (NB * FIN) + ax_base;
#pragma unroll
      for (int kk = 0; kk < 8; ++kk) {
        xpf[2 * kk]     = *(const f32x4*)(ap + kk * 32);
        xpf[2 * kk + 1] = *(const f32x4*)(ap + kk * 32 + 4);
      }
    } else if (t > 0) {
      // gather tagged h(t-1): merged detect+fetch polling.
      // u64 index map (as baseline): hv[i] at hb + (i>>2)*16 + quad*4 + (i&3).
      // Pair p (0..15) = u64s {(p>>1)*4+(p&1)*2, +1}; one 16B load each.
      const unsigned long long* hb =
          hbuf + (size_t)((t - 1) & 3) * HBUF_U64 + hrow_u64;
      const unsigned long long* hbq = hb + quad * 4;
      unsigned long long hv[32];
      unsigned int pend = 0xffffu;  // 16 pending pairs

      for (int r = 0; r < R_FAST && pend; ++r) {
        u32x4 wv[16];
#define ISSUE(p) if (pend & (1u << (p))) \
          wv[p] = ldx4_dev<(((p) >> 1) * 128 + ((p) & 1) * 16)>(hbq);
        ISSUE(0)  ISSUE(1)  ISSUE(2)  ISSUE(3)
        ISSUE(4)  ISSUE(5)  ISSUE(6)  ISSUE(7)
        ISSUE(8)  ISSUE(9)  ISSUE(10) ISSUE(11)
        ISSUE(12) ISSUE(13) ISSUE(14) ISSUE(15)
#undef ISSUE
        asm volatile("s_waitcnt vmcnt(0)" ::: "memory");
        __builtin_amdgcn_sched_barrier(0);  // rule 18: no use hoisted above wait
#pragma unroll
        for (int p = 0; p < 16; ++p)
          if (pend & (1u << p)) {
            int i0 = (p >> 1) * 4 + (p & 1) * 2;
            unsigned long long a =
                ((unsigned long long)wv[p][1] << 32) | wv[p][0];
            unsigned long long b =
                ((unsigned long long)wv[p][3] << 32) | wv[p][2];
            if ((int)(unsigned int)(a >> 32) >= t &&
                (int)(unsigned int)(b >> 32) >= t) {
              hv[i0] = a; hv[i0 + 1] = b;
              pend &= ~(1u << p);
            }
          }
      }
      if (pend) {
        // proven fallback: per-u64 agent atomics (byte-identical to baseline)
        unsigned int done = 0;
#pragma unroll
        for (int p = 0; p < 16; ++p)
          if (!(pend & (1u << p)))
            done |= 3u << ((p >> 1) * 4 + (p & 1) * 2);
        for (int r = 0; r < 8192 && done != 0xffffffffu; ++r) {
#pragma unroll
          for (int i = 0; i < 32; ++i)
            if (!((done >> i) & 1u))
              hv[i] = __hip_atomic_load(hb + ((i >> 2) * 16 + quad * 4 + (i & 3)),
                                        __ATOMIC_RELAXED, __HIP_MEMORY_SCOPE_AGENT);
          unsigned int nd = done;
#pragma unroll
          for (int i = 0; i < 32; ++i)
            if (!((nd >> i) & 1u) && (int)(unsigned int)(hv[i] >> 32) >= t)
              nd |= 1u << i;
          done = nd;
          if (done != 0xffffffffu) __builtin_amdgcn_s_sleep(1);
        }
      }

      bf16x8 afr[8];
#pragma unroll
      for (int kk = 0; kk < 8; ++kk) {
        union { unsigned int d[4]; bf16x8 v; } u;
#pragma unroll
        for (int j = 0; j < 4; ++j) u.d[j] = (unsigned int)hv[kk * 4 + j];
        afr[kk] = u.v;
      }
#pragma unroll
      for (int kk = 0; kk < 8; ++kk) {
        acc0 = __builtin_amdgcn_mfma_f32_16x16x32_bf16(afr[kk], bfrag[0][kk], acc0, 0, 0, 0);
        acc1 = __builtin_amdgcn_mfma_f32_16x16x32_bf16(afr[kk], bfrag[1][kk], acc1, 0, 0, 0);
      }
    }
    // C/D layout: col = lane&15 (= n), row m = quad*4 + reg
    *(f32x4*)&gred[t & 1][wave][nloc][quad * 4]      = acc0;
    *(f32x4*)&gred[t & 1][wave][16 + nloc][quad * 4] = acc1;
    __syncthreads();  // the only barrier per step (gred is double-buffered)

    if (tid < 128) {
      float gs[4];
#pragma unroll
      for (int g = 0; g < 4; ++g) {
        int n = g * 8 + cj;
        gs[g] = bias_[g] + gred[t & 1][0][n][cb] + gred[t & 1][1][n][cb] +
                gred[t & 1][2][n][cb] + gred[t & 1][3][n][cb];
      }
      float ig = sigm(gs[0]);
      float fg = sigm(gs[1]);
      float gg = tanh_(gs[2]);
      float og = sigm(gs[3]);
      float c  = fg * cprev + ig * gg;
      cprev = c;
      float h  = og * tanh_(c);
      size_t o = (size_t)t * (NB * HD) + (size_t)(mb0 + cb) * HD + hid0 + cj;
      // publish tagged h pair FIRST: even thread packs (cj, cj+1)
      unsigned int hu = (unsigned int)f2bf(h);
      unsigned int ho = __shfl_down(hu, 1);
      if ((tid & 1) == 0) {
        unsigned long long tv =
            ((unsigned long long)(unsigned int)(t + 1) << 32) |
            (unsigned long long)(hu | (ho << 16));
        int eidx = (mb0 + cb) * HD + hid0 + cj;  // cj even
        __hip_atomic_store(hbuf + (size_t)(t & 3) * HBUF_U64 + (eidx >> 1), tv,
                           __ATOMIC_RELAXED, __HIP_MEMORY_SCOPE_AGENT);
      }
      out[o] = h;
      out[(size_t)TS * NB * HD + o] = c;
    }
    // no second barrier: next step's gred writes hit buffer (t+1)&1
  }
}

extern "C" void kernel_launch(void* const* d_in, const int* in_sizes, int n_in,
                              void* d_out, int out_size, void* d_ws, size_t ws_size,
                              hipStream_t stream) {
  const float* seq = (const float*)d_in[0];
  const float* wih = (const float*)d_in[1];
  const float* whh = (const float*)d_in[2];
  const float* bih = (const float*)d_in[3];
  const float* bhh = (const float*)d_in[4];
  float* out = (float*)d_out;
  unsigned long long* hbuf = (unsigned long long*)d_ws;  // 4*16384*8 = 512 KiB
  hipLaunchKernelGGL(lstm_persist, dim3(256), dim3(256), 0, stream,
                     seq, wih, whh, bih, bhh, out, hbuf);
}

// Round 5
// 2262.394 us; speedup vs baseline: 6.6633x; 1.5016x over previous
//
#include <hip/hip_runtime.h>

#define TS 512
#define NB 64
#define FIN 512
#define HD 512
#define HBUF_U64 (NB * HD / 2)   // 16384 u64 per buffer; 4 buffers = 512 KiB in d_ws
#define R_FAST 16                // dwordx4 fast poll rounds before proven fallback

typedef short bf16x8 __attribute__((ext_vector_type(8)));
typedef float f32x4 __attribute__((ext_vector_type(4)));
typedef unsigned int u32x4 __attribute__((ext_vector_type(4)));

__device__ __forceinline__ unsigned short f2bf(float f) {
  union { float f; unsigned int i; } v; v.f = f;
  unsigned int r = v.i + 0x7fffu + ((v.i >> 16) & 1u);  // RNE
  return (unsigned short)(r >> 16);
}
__device__ __forceinline__ bf16x8 packv(f32x4 a, f32x4 b) {
  bf16x8 r;
#pragma unroll
  for (int i = 0; i < 4; ++i) r[i] = (short)f2bf(a[i]);
#pragma unroll
  for (int i = 0; i < 4; ++i) r[4 + i] = (short)f2bf(b[i]);
  return r;
}
__device__ __forceinline__ float sigm(float x) { return 1.0f / (1.0f + __expf(-x)); }
__device__ __forceinline__ float tanh_(float x) { return 1.0f - 2.0f / (__expf(2.0f * x) + 1.0f); }

// 16B device-coherent load: sc0 sc1 bypasses L1 AND the (per-XCD, stale-able)
// L2 -- same freshness path as agent-scope atomic loads (round-1 pinned).
// Result registers invalid until caller's s_waitcnt vmcnt(0).
template <int OFF>
__device__ __forceinline__ u32x4 ldx4_dev(const unsigned long long* p) {
  u32x4 v;
  asm volatile("global_load_dwordx4 %0, %1, off offset:%2 sc0 sc1"
               : "=v"(v) : "v"(p), "i"(OFF));
  return v;
}

// Persistent fused LSTM. fp32 in, fp32 out, bf16 MFMA internal.
// Grid: 256 WGs = 4 batch groups (bg) x 64 hidden groups (hg).
// WG(bg,hg): batches [bg*16,+16), hidden [hg*8,+8) -> 32 gate rows.
// Waves 0,1: x @ W_ih^T (K halves). Waves 2,3: h @ W_hh^T (K halves).
// Weights as bf16 fragments in registers for all 512 steps.
//
// h exchange: tagged u64 {tag=t+1 | 2xbf16} via RELAXED agent atomics, 4
// rotating buffers. ROUND-4 CHANGE: producer-major hbuf layout
//   u64 index = buf*16384 + (bg*64 + hg)*64 + cb*4 + j      (j = cj>>1)
// so each producer's 64-u64 publish is ONE contiguous 512B region (~8 line
// transactions at the IF coherence point instead of 64 batch-strided ones),
// and each consumer poll instruction reads 4 contiguous 512B regions instead
// of 64 scattered lines. Consumer fragment map: for MFMA step kk, lane
// (nloc,quad) needs producer hg = w*32 + kk*4 + quad, batch nloc, u64 j=0..3
// -> hv[kk*4+j] at u64 offset kk*256 + j from per-lane base. Poll structure
// (merged detect+fetch dwordx4 fast rounds + per-u64 tags + atomic-u64
// fallback) unchanged from the 3397us kernel.
__global__ void __launch_bounds__(256, 1) lstm_persist(
    const float* __restrict__ seq,
    const float* __restrict__ w_ih,
    const float* __restrict__ w_hh,
    const float* __restrict__ b_ih,
    const float* __restrict__ b_hh,
    float* __restrict__ out,
    unsigned long long* __restrict__ hbuf)  // [4][16384] tagged u64 in d_ws
{
  const int wg   = blockIdx.x;
  const int hg   = wg & 63;
  const int bg   = wg >> 6;
  const int tid  = threadIdx.x;
  const int wave = tid >> 6;
  const int lane = tid & 63;
  const int mb0  = bg * 16;
  const int hid0 = hg * 8;
  const int nloc = lane & 15;   // A: m (batch). B: n (gate col). C/D: col = n.
  const int quad = lane >> 4;   // A/B: k-chunk. C/D: row block (m).

  __shared__ __align__(16) float gred[2][4][32][20];  // [t&1][wave][n][m +pad]

  const float* W = (wave < 2) ? w_ih : w_hh;
  const int w   = wave & 1;         // K half selector
  const int k0  = w * 256;

  // ---- step-invariant weight fragments -> bf16 registers ----
  bf16x8 bfrag[2][8];  // [ntile][kiter]
#pragma unroll
  for (int nt = 0; nt < 2; ++nt) {
    int n = nt * 16 + nloc;
    int grow = (n >> 3) * HD + hid0 + (n & 7);  // gate row: gtype*512 + hid0 + j
    const float* src = W + (size_t)grow * FIN + k0 + quad * 8;
#pragma unroll
    for (int kk = 0; kk < 8; ++kk)
      bfrag[nt][kk] = packv(*(const f32x4*)(src + kk * 32),
                            *(const f32x4*)(src + kk * 32 + 4));
  }

  // ---- cell-thread state (threads 0..127: one (batch,hid) each) ----
  float bias_[4] = {0.f, 0.f, 0.f, 0.f};
  float cprev = 0.0f;
  int cb = 0, cj = 0;
  if (tid < 128) {
    cb = tid >> 3;   // local batch 0..15
    cj = tid & 7;    // local hid 0..7
#pragma unroll
    for (int g = 0; g < 4; ++g) {
      int r = g * HD + hid0 + cj;
      bias_[g] = b_ih[r] + b_hh[r];
    }
  }

  const size_t ax_base = (size_t)(mb0 + nloc) * FIN + k0 + quad * 8;
  // consumer per-lane base (u64 units, within one rotation buffer):
  //   bg*4096 + w*2048 + quad*64 + nloc*4; MFMA step kk at +kk*256, u64 j at +j
  const int rd_base = bg * 4096 + w * 2048 + quad * 64 + nloc * 4;
  // producer slot base (u64 units, within one rotation buffer):
  const int wr_base = (bg * 64 + hg) * 64;

  // ---- software-prefetch x(0) into registers (waves 0,1) ----
  f32x4 xpf[16];
  if (wave < 2) {
    const float* ap = seq + ax_base;
#pragma unroll
    for (int kk = 0; kk < 8; ++kk) {
      xpf[2 * kk]     = *(const f32x4*)(ap + kk * 32);
      xpf[2 * kk + 1] = *(const f32x4*)(ap + kk * 32 + 4);
    }
  }

  for (int t = 0; t < TS; ++t) {
    f32x4 acc0 = {0.f, 0.f, 0.f, 0.f};
    f32x4 acc1 = {0.f, 0.f, 0.f, 0.f};

    if (wave < 2) {
      // x-projection from prefetched regs; no cross-WG dependency
      bf16x8 afr[8];
#pragma unroll
      for (int kk = 0; kk < 8; ++kk) afr[kk] = packv(xpf[2 * kk], xpf[2 * kk + 1]);
#pragma unroll
      for (int kk = 0; kk < 8; ++kk) {
        acc0 = __builtin_amdgcn_mfma_f32_16x16x32_bf16(afr[kk], bfrag[0][kk], acc0, 0, 0, 0);
        acc1 = __builtin_amdgcn_mfma_f32_16x16x32_bf16(afr[kk], bfrag[1][kk], acc1, 0, 0, 0);
      }
      // prefetch x(t+1) (lands during the rest of this step)
      int tn = (t + 1 < TS) ? t + 1 : TS - 1;
      const float* ap = seq + (size_t)tn * (NB * FIN) + ax_base;
#pragma unroll
      for (int kk = 0; kk < 8; ++kk) {
        xpf[2 * kk]     = *(const f32x4*)(ap + kk * 32);
        xpf[2 * kk + 1] = *(const f32x4*)(ap + kk * 32 + 4);
      }
    } else if (t > 0) {
      // gather tagged h(t-1): merged detect+fetch polling, producer-major layout.
      // Pair p (0..15): kk = p>>1, u64s {kk*256 + (p&1)*2, +1}. Per-pair base
      // pointer + imm keeps the 13-bit offset in range.
      const unsigned long long* hb =
          hbuf + (size_t)((t - 1) & 3) * HBUF_U64 + rd_base;
      unsigned long long hv[32];
      unsigned int pend = 0xffffu;  // 16 pending pairs

      for (int r = 0; r < R_FAST && pend; ++r) {
        u32x4 wv[16];
#define ISSUE(p) if (pend & (1u << (p))) \
          wv[p] = ldx4_dev<((((p) >> 1) & 1) * 2048 + ((p) & 1) * 16)>( \
              hb + ((p) >> 2) * 512);
        ISSUE(0)  ISSUE(1)  ISSUE(2)  ISSUE(3)
        ISSUE(4)  ISSUE(5)  ISSUE(6)  ISSUE(7)
        ISSUE(8)  ISSUE(9)  ISSUE(10) ISSUE(11)
        ISSUE(12) ISSUE(13) ISSUE(14) ISSUE(15)
#undef ISSUE
        asm volatile("s_waitcnt vmcnt(0)" ::: "memory");
        __builtin_amdgcn_sched_barrier(0);  // rule 18: no use hoisted above wait
#pragma unroll
        for (int p = 0; p < 16; ++p)
          if (pend & (1u << p)) {
            int i0 = (p >> 1) * 4 + (p & 1) * 2;
            unsigned long long a =
                ((unsigned long long)wv[p][1] << 32) | wv[p][0];
            unsigned long long b =
                ((unsigned long long)wv[p][3] << 32) | wv[p][2];
            if ((int)(unsigned int)(a >> 32) >= t &&
                (int)(unsigned int)(b >> 32) >= t) {
              hv[i0] = a; hv[i0 + 1] = b;
              pend &= ~(1u << p);
            }
          }
      }
      if (pend) {
        // proven fallback: per-u64 agent atomics (same addresses, new layout)
        unsigned int done = 0;
#pragma unroll
        for (int p = 0; p < 16; ++p)
          if (!(pend & (1u << p)))
            done |= 3u << ((p >> 1) * 4 + (p & 1) * 2);
        for (int r = 0; r < 8192 && done != 0xffffffffu; ++r) {
#pragma unroll
          for (int i = 0; i < 32; ++i)
            if (!((done >> i) & 1u))
              hv[i] = __hip_atomic_load(hb + ((i >> 2) * 256 + (i & 3)),
                                        __ATOMIC_RELAXED, __HIP_MEMORY_SCOPE_AGENT);
          unsigned int nd = done;
#pragma unroll
          for (int i = 0; i < 32; ++i)
            if (!((nd >> i) & 1u) && (int)(unsigned int)(hv[i] >> 32) >= t)
              nd |= 1u << i;
          done = nd;
          if (done != 0xffffffffu) __builtin_amdgcn_s_sleep(1);
        }
      }

      bf16x8 afr[8];
#pragma unroll
      for (int kk = 0; kk < 8; ++kk) {
        union { unsigned int d[4]; bf16x8 v; } u;
#pragma unroll
        for (int j = 0; j < 4; ++j) u.d[j] = (unsigned int)hv[kk * 4 + j];
        afr[kk] = u.v;
      }
#pragma unroll
      for (int kk = 0; kk < 8; ++kk) {
        acc0 = __builtin_amdgcn_mfma_f32_16x16x32_bf16(afr[kk], bfrag[0][kk], acc0, 0, 0, 0);
        acc1 = __builtin_amdgcn_mfma_f32_16x16x32_bf16(afr[kk], bfrag[1][kk], acc1, 0, 0, 0);
      }
    }
    // C/D layout: col = lane&15 (= n), row m = quad*4 + reg
    *(f32x4*)&gred[t & 1][wave][nloc][quad * 4]      = acc0;
    *(f32x4*)&gred[t & 1][wave][16 + nloc][quad * 4] = acc1;
    __syncthreads();  // the only barrier per step (gred is double-buffered)

    if (tid < 128) {
      float gs[4];
#pragma unroll
      for (int g = 0; g < 4; ++g) {
        int n = g * 8 + cj;
        gs[g] = bias_[g] + gred[t & 1][0][n][cb] + gred[t & 1][1][n][cb] +
                gred[t & 1][2][n][cb] + gred[t & 1][3][n][cb];
      }
      float ig = sigm(gs[0]);
      float fg = sigm(gs[1]);
      float gg = tanh_(gs[2]);
      float og = sigm(gs[3]);
      float c  = fg * cprev + ig * gg;
      cprev = c;
      float h  = og * tanh_(c);
      size_t o = (size_t)t * (NB * HD) + (size_t)(mb0 + cb) * HD + hid0 + cj;
      // publish tagged h pair FIRST: even thread packs (cj, cj+1).
      // Producer-major slot: contiguous 512B per WG -> ~8 coherence-point
      // line transactions per step instead of 64.
      unsigned int hu = (unsigned int)f2bf(h);
      unsigned int ho = __shfl_down(hu, 1);
      if ((tid & 1) == 0) {
        unsigned long long tv =
            ((unsigned long long)(unsigned int)(t + 1) << 32) |
            (unsigned long long)(hu | (ho << 16));
        __hip_atomic_store(hbuf + (size_t)(t & 3) * HBUF_U64 + wr_base +
                               cb * 4 + (cj >> 1), tv,
                           __ATOMIC_RELAXED, __HIP_MEMORY_SCOPE_AGENT);
      }
      out[o] = h;
      out[(size_t)TS * NB * HD + o] = c;
    }
    // no second barrier: next step's gred writes hit buffer (t+1)&1
  }
}

extern "C" void kernel_launch(void* const* d_in, const int* in_sizes, int n_in,
                              void* d_out, int out_size, void* d_ws, size_t ws_size,
                              hipStream_t stream) {
  const float* seq = (const float*)d_in[0];
  const float* wih = (const float*)d_in[1];
  const float* whh = (const float*)d_in[2];
  const float* bih = (const float*)d_in[3];
  const float* bhh = (const float*)d_in[4];
  float* out = (float*)d_out;
  unsigned long long* hbuf = (unsigned long long*)d_ws;  // 4*16384*8 = 512 KiB
  hipLaunchKernelGGL(lstm_persist, dim3(256), dim3(256), 0, stream,
                     seq, wih, whh, bih, bhh, out, hbuf);
}